// Round 2
// baseline (732.248 us; speedup 1.0000x reference)
//
#include <hip/hip_runtime.h>
#include <hip/hip_fp16.h>

typedef __attribute__((ext_vector_type(4))) float f32x4;
typedef __attribute__((ext_vector_type(8))) _Float16 f16x8;
typedef __attribute__((ext_vector_type(4))) _Float16 f16x4;

// ---------------- helpers ----------------
__device__ __forceinline__ void gload_lds16(const void* gp, void* lp) {
    __builtin_amdgcn_global_load_lds(
        (const __attribute__((address_space(1))) void*)gp,
        (__attribute__((address_space(3))) void*)lp, 16, 0, 0);
}

// ---------------- f32 -> f16 straight convert ----------------
__global__ void f32_to_f16_vec(const float* __restrict__ in, _Float16* __restrict__ out) {
    long i = ((long)blockIdx.x * 256 + threadIdx.x) * 4;
    f32x4 v = *(const f32x4*)(in + i);
    f16x4 h;
#pragma unroll
    for (int e = 0; e < 4; ++e) h[e] = (_Float16)v[e];
    *(f16x4*)(out + i) = h;
}

// ---------------- transpose + convert: in (R x C) f32 -> out (C x R) f16 ----------------
__global__ void transpose_f32_to_f16(const float* __restrict__ in, _Float16* __restrict__ out,
                                     int R, int C) {
    __shared__ _Float16 tile[32][36];
    const int c0 = blockIdx.x * 32, r0 = blockIdx.y * 32;
    const int t = threadIdx.x;
    const int r = t >> 3, c4 = (t & 7) * 4;
    f32x4 v = *(const f32x4*)(in + (long)(r0 + r) * C + c0 + c4);
    f16x4 h;
#pragma unroll
    for (int e = 0; e < 4; ++e) h[e] = (_Float16)v[e];
    *(f16x4*)&tile[r][c4] = h;
    __syncthreads();
    const int oc = t >> 3, o4 = (t & 7) * 4;
    f16x4 o;
#pragma unroll
    for (int e = 0; e < 4; ++e) o[e] = tile[o4 + e][oc];
    *(f16x4*)(out + (long)(c0 + oc) * R + r0 + o4) = o;
}

// ---------------- RoPE in-place on qkv rows (head-mixing: pair j with j+1024) ----------------
__global__ void rope_inplace(_Float16* __restrict__ qkv) {
    const int row = blockIdx.x;            // b*2048 + s
    const int s = row & 2047;
    const int j0 = threadIdx.x * 4;        // [0,1024)
    _Float16* base = qkv + (long)row * 6144;
    f16x4 q0 = *(const f16x4*)(base + j0);
    f16x4 q1 = *(const f16x4*)(base + 1024 + j0);
    f16x4 k0 = *(const f16x4*)(base + 2048 + j0);
    f16x4 k1 = *(const f16x4*)(base + 3072 + j0);
    f16x4 oq0, oq1, ok0, ok1;
#pragma unroll
    for (int e = 0; e < 4; ++e) {
        int fi = (j0 + e) & 511;
        float expo = (float)(2 * fi) * (1.0f / 1024.0f);
        float invf = 1.0f / powf(10000.0f, expo);
        float ang = (float)s * invf;
        float sn, cs;
        sincosf(ang, &sn, &cs);
        float a = (float)q0[e], b = (float)q1[e];
        oq0[e] = (_Float16)(a * cs - b * sn);
        oq1[e] = (_Float16)(b * cs + a * sn);
        float c = (float)k0[e], d = (float)k1[e];
        ok0[e] = (_Float16)(c * cs - d * sn);
        ok1[e] = (_Float16)(d * cs + c * sn);
    }
    *(f16x4*)(base + j0) = oq0;
    *(f16x4*)(base + 1024 + j0) = oq1;
    *(f16x4*)(base + 2048 + j0) = ok0;
    *(f16x4*)(base + 3072 + j0) = ok1;
}

// ---------------- V transpose: qkv v-part (b,s,h,d) -> vT (b,h,d,s) f16 ----------------
__global__ void v_transpose(const _Float16* __restrict__ qkv, _Float16* __restrict__ vT) {
    __shared__ _Float16 tile[32][36];
    const int z = blockIdx.z, b = z >> 1, h = z & 1;
    const int s0 = blockIdx.x * 32, d0 = blockIdx.y * 32;
    const int t = threadIdx.x;
    const int r = t >> 3, c4 = (t & 7) * 4;    // r = s-local, c4 = d-local
    const _Float16* src = qkv + (long)(b * 2048 + s0 + r) * 6144 + 4096 + h * 1024 + d0 + c4;
    *(f16x4*)&tile[r][c4] = *(const f16x4*)src;
    __syncthreads();
    const int dr = t >> 3, sc = (t & 7) * 4;
    f16x4 o;
#pragma unroll
    for (int e = 0; e < 4; ++e) o[e] = tile[sc + e][dr];
    *(f16x4*)(vT + ((long)z * 1024 + d0 + dr) * 2048 + s0 + sc) = o;
}

// ---------------- softmax on f32 rows (2048), writes f16 P in place (row stride 4096 f16) ----------------
__global__ __launch_bounds__(256) void softmax_rows_f32(float* __restrict__ S, float scale) {
    const int wid = threadIdx.x >> 6, lane = threadIdx.x & 63;
    const long row = (long)blockIdx.x * 4 + wid;
    float* rp = S + row * 2048;
    f32x4 v[8];
    float mx = -1e30f;
#pragma unroll
    for (int i = 0; i < 8; ++i) {
        v[i] = *(const f32x4*)(rp + (i * 64 + lane) * 4);
#pragma unroll
        for (int e = 0; e < 4; ++e) mx = fmaxf(mx, v[i][e]);
    }
#pragma unroll
    for (int o = 32; o > 0; o >>= 1) mx = fmaxf(mx, __shfl_xor(mx, o, 64));
    float sum = 0.f;
#pragma unroll
    for (int i = 0; i < 8; ++i)
#pragma unroll
        for (int e = 0; e < 4; ++e) {
            float p = __expf(scale * (v[i][e] - mx));
            v[i][e] = p; sum += p;
        }
#pragma unroll
    for (int o = 32; o > 0; o >>= 1) sum += __shfl_xor(sum, o, 64);
    float inv = 1.0f / sum;
    _Float16* wp = (_Float16*)S + row * 4096;
#pragma unroll
    for (int i = 0; i < 8; ++i) {
        f16x4 h;
#pragma unroll
        for (int e = 0; e < 4; ++e) h[e] = (_Float16)(v[i][e] * inv);
        *(f16x4*)(wp + (i * 64 + lane) * 4) = h;
    }
}

// ---------------- softmax on f16 rows (2048), in place (row stride 2048 f16) ----------------
__global__ __launch_bounds__(256) void softmax_rows_f16(_Float16* __restrict__ S, float scale) {
    const int wid = threadIdx.x >> 6, lane = threadIdx.x & 63;
    const long row = (long)blockIdx.x * 4 + wid;
    _Float16* rp = S + row * 2048;
    f16x8 v[4];
    float f[32];
    float mx = -1e30f;
#pragma unroll
    for (int i = 0; i < 4; ++i) {
        v[i] = *(const f16x8*)(rp + i * 512 + lane * 8);
#pragma unroll
        for (int e = 0; e < 8; ++e) {
            f[i * 8 + e] = (float)v[i][e];
            mx = fmaxf(mx, f[i * 8 + e]);
        }
    }
#pragma unroll
    for (int o = 32; o > 0; o >>= 1) mx = fmaxf(mx, __shfl_xor(mx, o, 64));
    float sum = 0.f;
#pragma unroll
    for (int i = 0; i < 32; ++i) {
        float p = __expf(scale * (f[i] - mx));
        f[i] = p; sum += p;
    }
#pragma unroll
    for (int o = 32; o > 0; o >>= 1) sum += __shfl_xor(sum, o, 64);
    float inv = 1.0f / sum;
#pragma unroll
    for (int i = 0; i < 4; ++i) {
        f16x8 h;
#pragma unroll
        for (int e = 0; e < 8; ++e) h[e] = (_Float16)(f[i * 8 + e] * inv);
        *(f16x8*)(rp + i * 512 + lane * 8) = h;
    }
}

// ---------------- GEMM: C = A(MxK, lda) * B^T (B stored NxK row-major, ldb) ----------------
// 128x128 tile, BK=32, 4 waves, mfma_f32_16x16x32_f16, global_load_lds staging.
// Per-z offsets: zq=z/zmod, zr=z%zmod; A += zq*a1+zr*a2; B += zq*b1+zr*b2; C += zq*c1+zr*c2.
template <bool OUT_F16, bool BIAS>
__global__ __launch_bounds__(256)
void gemm_bt(const _Float16* __restrict__ A, const _Float16* __restrict__ B,
             void* __restrict__ Cv, const float* __restrict__ bias,
             int K, int lda, int ldb, int ldc, int zmod,
             long a1, long a2, long b1, long b2, long c1, long c2) {
    __shared__ _Float16 lA[4096];
    __shared__ _Float16 lB[4096];
    const int z = blockIdx.z, zq = z / zmod, zr = z - zq * zmod;
    A += zq * a1 + zr * a2;
    B += zq * b1 + zr * b2;
    const long coff = zq * c1 + zr * c2;
    const int tm = blockIdx.y * 128, tn = blockIdx.x * 128;
    const int t = threadIdx.x;
    const int lane = t & 63;
    const int wid = t >> 6;
    const int wr = (wid >> 1) * 64, wc = (wid & 1) * 64;
    const int fr = lane & 15;
    const int kb = (lane >> 4) * 16;          // byte offset of k-chunk in a 64B LDS row

    f32x4 acc[4][4] = {};

    const int srow = t >> 2;                  // 0..63 staging row within 64-row group
    const int scol = (t & 3) * 8;             // staging k element offset
    const int lwave = wid * 1024;             // per-wave LDS byte base per issue

    const _Float16* ga = A + (long)(tm + srow) * lda + scol;
    const _Float16* gb = B + (long)(tn + srow) * ldb + scol;

    for (int k0 = 0; k0 < K; k0 += 32) {
        gload_lds16(ga + k0,                  (char*)lA + lwave);
        gload_lds16(ga + (long)64 * lda + k0, (char*)lA + 4096 + lwave);
        gload_lds16(gb + k0,                  (char*)lB + lwave);
        gload_lds16(gb + (long)64 * ldb + k0, (char*)lB + 4096 + lwave);
        __syncthreads();
        f16x8 af[4], bf[4];
#pragma unroll
        for (int m = 0; m < 4; ++m)
            af[m] = *(const f16x8*)((const char*)lA + (wr + m * 16 + fr) * 64 + kb);
#pragma unroll
        for (int n = 0; n < 4; ++n)
            bf[n] = *(const f16x8*)((const char*)lB + (wc + n * 16 + fr) * 64 + kb);
#pragma unroll
        for (int m = 0; m < 4; ++m)
#pragma unroll
            for (int n = 0; n < 4; ++n)
                acc[m][n] = __builtin_amdgcn_mfma_f32_16x16x32_f16(af[m], bf[n], acc[m][n], 0, 0, 0);
        __syncthreads();
    }

    // epilogue: C/D layout col = lane&15, row = (lane>>4)*4 + r
    const int rb = tm + wr + (lane >> 4) * 4;
    const int cb = tn + wc + fr;
#pragma unroll
    for (int m = 0; m < 4; ++m) {
#pragma unroll
        for (int n = 0; n < 4; ++n) {
#pragma unroll
            for (int r = 0; r < 4; ++r) {
                float v = acc[m][n][r];
                const int row = rb + m * 16 + r;
                const int col = cb + n * 16;
                if (BIAS) v += bias[col];
                if (OUT_F16)
                    ((_Float16*)Cv)[coff + (long)row * ldc + col] = (_Float16)v;
                else
                    ((float*)Cv)[coff + (long)row * ldc + col] = v;
            }
        }
    }
}

extern "C" void kernel_launch(void* const* d_in, const int* in_sizes, int n_in,
                              void* d_out, int out_size, void* d_ws, size_t ws_size,
                              hipStream_t stream) {
    const float* x    = (const float*)d_in[0];   // (4,2048,2048)
    const float* wqkv = (const float*)d_in[1];   // (2048,6144)
    const float* wout = (const float*)d_in[2];   // (2048,2048)
    const float* bout = (const float*)d_in[3];   // (2048,)
    char* ws = (char*)d_ws;

    // Workspace layout (aliased by lifetime):
    //   qkv_h  [0,          100663296)  f16 (b,s,3*2048); q,k rotated in place
    //   x_h    [100663296,  134217728)  f16; dead after QKV GEMM
    //   wqkvT  [134217728,  159383552)  f16; dead after QKV GEMM
    //   vT     = alias x_h region                      (written after QKV GEMM)
    //   woutT  = alias qkv_h[0,8.4M)                   (written after attention)
    // per-z path  (peak 184,549,376 B):
    //   S32    [134217728,  150994944)  f32 2048x2048, alias wqkvT
    //   aout   [150994944,  184549376)  f16
    // batched path (peak 234,881,024 B):
    //   S16    [134217728,  201326592)  f16 8x2048x2048, alias wqkvT
    //   aout   [201326592,  234881024)  f16
    _Float16* qkv_h = (_Float16*)(ws);
    _Float16* x_h   = (_Float16*)(ws + 100663296);
    _Float16* wqkvT = (_Float16*)(ws + 134217728);
    _Float16* vT    = (_Float16*)(ws + 100663296);
    _Float16* woutT = (_Float16*)(ws);
    const bool batched = ws_size >= 234881024ULL;

    // 1. x -> f16
    f32_to_f16_vec<<<dim3(16384), dim3(256), 0, stream>>>(x, x_h);
    // 2. wqkv (2048x6144) -> wqkvT (6144x2048) f16
    transpose_f32_to_f16<<<dim3(192, 64), dim3(256), 0, stream>>>(wqkv, wqkvT, 2048, 6144);
    // 3. qkv = x @ wqkv  (M=8192,N=6144,K=2048) -> f16
    gemm_bt<true, false><<<dim3(48, 64, 1), dim3(256), 0, stream>>>(
        x_h, wqkvT, (void*)qkv_h, nullptr, 2048, 2048, 2048, 6144,
        1, 0L, 0L, 0L, 0L, 0L, 0L);
    // 4. RoPE in place on q,k halves (head-mixing rotation)
    rope_inplace<<<dim3(8192), dim3(256), 0, stream>>>(qkv_h);
    // 5. V transpose -> vT (b,h,d,s)
    v_transpose<<<dim3(64, 32, 8), dim3(256), 0, stream>>>(qkv_h, vT);

    if (batched) {
        _Float16* S16  = (_Float16*)(ws + 134217728);
        _Float16* aout = (_Float16*)(ws + 201326592);
        // 6. S = Q@K^T all 8 (b,h): A=q slice of qkv, B=k slice; M=N=2048,K=1024 -> f16
        gemm_bt<true, false><<<dim3(16, 16, 8), dim3(256), 0, stream>>>(
            qkv_h, qkv_h + 2048, (void*)S16, nullptr, 1024, 6144, 6144, 2048,
            2, 12582912L, 1024L, 12582912L, 1024L, 8388608L, 4194304L);
        // 7. softmax rows in place
        softmax_rows_f16<<<dim3(4096), dim3(256), 0, stream>>>(S16, 0.03125f);
        // 8. O = P@V: M=2048,N=1024,K=2048 -> aout (b,s,h*d)
        gemm_bt<true, false><<<dim3(8, 16, 8), dim3(256), 0, stream>>>(
            S16, vT, (void*)aout, nullptr, 2048, 2048, 2048, 2048,
            2, 8388608L, 4194304L, 4194304L, 2097152L, 4194304L, 1024L);
        // 9. wout -> woutT; out = aout @ wout + bout
        transpose_f32_to_f16<<<dim3(64, 64), dim3(256), 0, stream>>>(wout, woutT, 2048, 2048);
        gemm_bt<false, true><<<dim3(16, 64, 1), dim3(256), 0, stream>>>(
            aout, woutT, d_out, bout, 2048, 2048, 2048, 2048,
            1, 0L, 0L, 0L, 0L, 0L, 0L);
    } else {
        float*    S32  = (float*)(ws + 134217728);
        _Float16* aout = (_Float16*)(ws + 150994944);
        for (int z = 0; z < 8; ++z) {
            const _Float16* Az = qkv_h + (long)(z >> 1) * 12582912 + (z & 1) * 1024;
            gemm_bt<false, false><<<dim3(16, 16, 1), dim3(256), 0, stream>>>(
                Az, Az + 2048, (void*)S32, nullptr, 1024, 6144, 6144, 2048,
                1, 0L, 0L, 0L, 0L, 0L, 0L);
            softmax_rows_f32<<<dim3(512), dim3(256), 0, stream>>>(S32, 0.03125f);
            gemm_bt<true, false><<<dim3(8, 16, 1), dim3(256), 0, stream>>>(
                (const _Float16*)S32, vT + (long)z * 2097152,
                (void*)(aout + (long)(z >> 1) * 4194304 + (z & 1) * 1024), nullptr,
                2048, 4096, 2048, 2048, 1, 0L, 0L, 0L, 0L, 0L, 0L);
        }
        transpose_f32_to_f16<<<dim3(64, 64), dim3(256), 0, stream>>>(wout, woutT, 2048, 2048);
        gemm_bt<false, true><<<dim3(16, 64, 1), dim3(256), 0, stream>>>(
            aout, woutT, d_out, bout, 2048, 2048, 2048, 2048,
            1, 0L, 0L, 0L, 0L, 0L, 0L);
    }
}

// Round 3
// 548.904 us; speedup vs baseline: 1.3340x; 1.3340x over previous
//
#include <hip/hip_runtime.h>
#include <hip/hip_fp16.h>

typedef __attribute__((ext_vector_type(4))) float f32x4;
typedef __attribute__((ext_vector_type(8))) _Float16 f16x8;
typedef __attribute__((ext_vector_type(4))) _Float16 f16x4;

// ---------------- helpers ----------------
__device__ __forceinline__ void gload_lds16(const void* gp, void* lp) {
    __builtin_amdgcn_global_load_lds(
        (const __attribute__((address_space(1))) void*)gp,
        (__attribute__((address_space(3))) void*)lp, 16, 0, 0);
}

// ---------------- f32 -> f16 straight convert ----------------
__global__ void f32_to_f16_vec(const float* __restrict__ in, _Float16* __restrict__ out) {
    long i = ((long)blockIdx.x * 256 + threadIdx.x) * 4;
    f32x4 v = *(const f32x4*)(in + i);
    f16x4 h;
#pragma unroll
    for (int e = 0; e < 4; ++e) h[e] = (_Float16)v[e];
    *(f16x4*)(out + i) = h;
}

// ---------------- transpose + convert: in (R x C) f32 -> out (C x R) f16 ----------------
__global__ void transpose_f32_to_f16(const float* __restrict__ in, _Float16* __restrict__ out,
                                     int R, int C) {
    __shared__ _Float16 tile[32][36];
    const int c0 = blockIdx.x * 32, r0 = blockIdx.y * 32;
    const int t = threadIdx.x;
    const int r = t >> 3, c4 = (t & 7) * 4;
    f32x4 v = *(const f32x4*)(in + (long)(r0 + r) * C + c0 + c4);
    f16x4 h;
#pragma unroll
    for (int e = 0; e < 4; ++e) h[e] = (_Float16)v[e];
    *(f16x4*)&tile[r][c4] = h;
    __syncthreads();
    const int oc = t >> 3, o4 = (t & 7) * 4;
    f16x4 o;
#pragma unroll
    for (int e = 0; e < 4; ++e) o[e] = tile[o4 + e][oc];
    *(f16x4*)(out + (long)(c0 + oc) * R + r0 + o4) = o;
}

// ---------------- RoPE in-place on qkv rows (head-mixing: pair j with j+1024) ----------------
__global__ void rope_inplace(_Float16* __restrict__ qkv) {
    const int row = blockIdx.x;            // b*2048 + s
    const int s = row & 2047;
    const int j0 = threadIdx.x * 4;        // [0,1024)
    _Float16* base = qkv + (long)row * 6144;
    f16x4 q0 = *(const f16x4*)(base + j0);
    f16x4 q1 = *(const f16x4*)(base + 1024 + j0);
    f16x4 k0 = *(const f16x4*)(base + 2048 + j0);
    f16x4 k1 = *(const f16x4*)(base + 3072 + j0);
    f16x4 oq0, oq1, ok0, ok1;
#pragma unroll
    for (int e = 0; e < 4; ++e) {
        int fi = (j0 + e) & 511;
        float expo = (float)(2 * fi) * (1.0f / 1024.0f);
        float invf = 1.0f / powf(10000.0f, expo);
        float ang = (float)s * invf;
        float sn, cs;
        sincosf(ang, &sn, &cs);
        float a = (float)q0[e], b = (float)q1[e];
        oq0[e] = (_Float16)(a * cs - b * sn);
        oq1[e] = (_Float16)(b * cs + a * sn);
        float c = (float)k0[e], d = (float)k1[e];
        ok0[e] = (_Float16)(c * cs - d * sn);
        ok1[e] = (_Float16)(d * cs + c * sn);
    }
    *(f16x4*)(base + j0) = oq0;
    *(f16x4*)(base + 1024 + j0) = oq1;
    *(f16x4*)(base + 2048 + j0) = ok0;
    *(f16x4*)(base + 3072 + j0) = ok1;
}

// ---------------- V transpose: qkv v-part (b,s,h,d) -> vT (b,h,d,s) f16 ----------------
__global__ void v_transpose(const _Float16* __restrict__ qkv, _Float16* __restrict__ vT) {
    __shared__ _Float16 tile[32][36];
    const int z = blockIdx.z, b = z >> 1, h = z & 1;
    const int s0 = blockIdx.x * 32, d0 = blockIdx.y * 32;
    const int t = threadIdx.x;
    const int r = t >> 3, c4 = (t & 7) * 4;
    const _Float16* src = qkv + (long)(b * 2048 + s0 + r) * 6144 + 4096 + h * 1024 + d0 + c4;
    *(f16x4*)&tile[r][c4] = *(const f16x4*)src;
    __syncthreads();
    const int dr = t >> 3, sc = (t & 7) * 4;
    f16x4 o;
#pragma unroll
    for (int e = 0; e < 4; ++e) o[e] = tile[sc + e][dr];
    *(f16x4*)(vT + ((long)z * 1024 + d0 + dr) * 2048 + s0 + sc) = o;
}

// ---------------- softmax on f32 rows (2048), writes f16 P in place (row stride 4096 f16) ----------------
__global__ __launch_bounds__(256) void softmax_rows_f32(float* __restrict__ S, float scale) {
    const int wid = threadIdx.x >> 6, lane = threadIdx.x & 63;
    const long row = (long)blockIdx.x * 4 + wid;
    float* rp = S + row * 2048;
    f32x4 v[8];
    float mx = -1e30f;
#pragma unroll
    for (int i = 0; i < 8; ++i) {
        v[i] = *(const f32x4*)(rp + (i * 64 + lane) * 4);
#pragma unroll
        for (int e = 0; e < 4; ++e) mx = fmaxf(mx, v[i][e]);
    }
#pragma unroll
    for (int o = 32; o > 0; o >>= 1) mx = fmaxf(mx, __shfl_xor(mx, o, 64));
    float sum = 0.f;
#pragma unroll
    for (int i = 0; i < 8; ++i)
#pragma unroll
        for (int e = 0; e < 4; ++e) {
            float p = __expf(scale * (v[i][e] - mx));
            v[i][e] = p; sum += p;
        }
#pragma unroll
    for (int o = 32; o > 0; o >>= 1) sum += __shfl_xor(sum, o, 64);
    float inv = 1.0f / sum;
    _Float16* wp = (_Float16*)S + row * 4096;
#pragma unroll
    for (int i = 0; i < 8; ++i) {
        f16x4 h;
#pragma unroll
        for (int e = 0; e < 4; ++e) h[e] = (_Float16)(v[i][e] * inv);
        *(f16x4*)(wp + (i * 64 + lane) * 4) = h;
    }
}

// ---------------- softmax on f16 rows (2048), in place (row stride 2048 f16) ----------------
__global__ __launch_bounds__(256) void softmax_rows_f16(_Float16* __restrict__ S, float scale) {
    const int wid = threadIdx.x >> 6, lane = threadIdx.x & 63;
    const long row = (long)blockIdx.x * 4 + wid;
    _Float16* rp = S + row * 2048;
    f16x8 v[4];
    float f[32];
    float mx = -1e30f;
#pragma unroll
    for (int i = 0; i < 4; ++i) {
        v[i] = *(const f16x8*)(rp + i * 512 + lane * 8);
#pragma unroll
        for (int e = 0; e < 8; ++e) {
            f[i * 8 + e] = (float)v[i][e];
            mx = fmaxf(mx, f[i * 8 + e]);
        }
    }
#pragma unroll
    for (int o = 32; o > 0; o >>= 1) mx = fmaxf(mx, __shfl_xor(mx, o, 64));
    float sum = 0.f;
#pragma unroll
    for (int i = 0; i < 32; ++i) {
        float p = __expf(scale * (f[i] - mx));
        f[i] = p; sum += p;
    }
#pragma unroll
    for (int o = 32; o > 0; o >>= 1) sum += __shfl_xor(sum, o, 64);
    float inv = 1.0f / sum;
#pragma unroll
    for (int i = 0; i < 4; ++i) {
        f16x8 h;
#pragma unroll
        for (int e = 0; e < 8; ++e) h[e] = (_Float16)(f[i * 8 + e] * inv);
        *(f16x8*)(rp + i * 512 + lane * 8) = h;
    }
}

// ---------------- GEMM 256x256, BK=32, 8 waves, 4-slot LDS ring, counted vmcnt ----------------
// C = A(MxK, lda) * B^T (B stored NxK row-major, ldb). LDS swizzle: granule ^= (row>>1)&3,
// applied via inverse-swizzled global source (rule: global_load_lds dest must be linear).
template <bool OUT_F16, bool BIAS>
__global__ __launch_bounds__(512, 2)
void gemm256(const _Float16* __restrict__ A, const _Float16* __restrict__ B,
             void* __restrict__ Cv, const float* __restrict__ bias,
             int K, int lda, int ldb, int ldc, int zmod,
             long a1, long a2, long b1, long b2, long c1, long c2) {
    __shared__ char lds[131072];   // A: 4 slots x 16 KB, B: +65536
    const int z = blockIdx.z, zq = z / zmod, zr = z - zq * zmod;
    A += zq * a1 + zr * a2;
    B += zq * b1 + zr * b2;
    const long coff = zq * c1 + zr * c2;
    const int tm = blockIdx.y * 256, tn = blockIdx.x * 256;
    const int t = threadIdx.x;
    const int lane = t & 63, wid = t >> 6;
    const int wr = wid >> 2, wc = wid & 3;     // wave tile: rows wr*128, cols wc*64
    const int fr = lane & 15;

    // staging: per wave 2 instrs/operand/tile; lane source pre-swizzled (involution)
    const int scol = 8 * ((lane & 3) ^ ((lane >> 3) & 3));
    const int srow = wid * 32 + (lane >> 2);
    const _Float16* gA = A + (long)(tm + srow) * lda + scol;
    const _Float16* gB = B + (long)(tn + srow) * ldb + scol;
    char* lA = lds + wid * 2048;
    char* lB = lds + 65536 + wid * 2048;

    // ds_read offsets (swizzled granule)
    const int gsw = 16 * ((lane >> 4) ^ ((fr >> 1) & 3));
    const int aoff = (wr * 128 + fr) * 64 + gsw;
    const int boff = 65536 + (wc * 64 + fr) * 64 + gsw;

    const int NT = K >> 5;
    f32x4 acc[8][4] = {};

    auto stageA = [&](int tt) {
        const int so = (tt & 3) * 16384;
        const long ko = (long)tt * 32;
        gload_lds16(gA + ko, lA + so);
        gload_lds16(gA + ko + (long)16 * lda, lA + so + 1024);
    };
    auto stageB = [&](int tt) {
        const int so = (tt & 3) * 16384;
        const long ko = (long)tt * 32;
        gload_lds16(gB + ko, lB + so);
        gload_lds16(gB + ko + (long)16 * ldb, lB + so + 1024);
    };

    stageA(0); stageB(0); stageA(1); stageB(1); stageA(2); stageB(2);

    for (int tt = 0; tt < NT; ++tt) {
        // gate: tile tt must be resident; never drain in steady state
        if (tt + 3 <= NT)      asm volatile("s_waitcnt vmcnt(8)" ::: "memory");
        else if (tt + 2 == NT) asm volatile("s_waitcnt vmcnt(4)" ::: "memory");
        else                   asm volatile("s_waitcnt vmcnt(0)" ::: "memory");
        __builtin_amdgcn_s_barrier();
        __builtin_amdgcn_sched_barrier(0);
        const char* st = lds + (tt & 3) * 16384;
        f16x8 af[8], bf[4];
        // phase 0: lower half A frags + all B frags; prefetch A of tile tt+3
#pragma unroll
        for (int m = 0; m < 4; ++m) af[m] = *(const f16x8*)(st + aoff + m * 1024);
#pragma unroll
        for (int n = 0; n < 4; ++n) bf[n] = *(const f16x8*)(st + boff + n * 1024);
        if (tt + 3 < NT) stageA(tt + 3);
        __builtin_amdgcn_s_barrier();
        __builtin_amdgcn_sched_barrier(0);
        __builtin_amdgcn_s_setprio(1);
#pragma unroll
        for (int m = 0; m < 4; ++m)
#pragma unroll
            for (int n = 0; n < 4; ++n)
                acc[m][n] = __builtin_amdgcn_mfma_f32_16x16x32_f16(af[m], bf[n], acc[m][n], 0, 0, 0);
        __builtin_amdgcn_s_setprio(0);
        // phase 1: upper half A frags; prefetch B of tile tt+3
#pragma unroll
        for (int m = 4; m < 8; ++m) af[m] = *(const f16x8*)(st + aoff + m * 1024);
        if (tt + 3 < NT) stageB(tt + 3);
        __builtin_amdgcn_s_barrier();
        __builtin_amdgcn_sched_barrier(0);
        __builtin_amdgcn_s_setprio(1);
#pragma unroll
        for (int m = 4; m < 8; ++m)
#pragma unroll
            for (int n = 0; n < 4; ++n)
                acc[m][n] = __builtin_amdgcn_mfma_f32_16x16x32_f16(af[m], bf[n], acc[m][n], 0, 0, 0);
        __builtin_amdgcn_s_setprio(0);
    }

    // epilogue: C/D layout col = lane&15, row = (lane>>4)*4 + r
    const int rb = tm + wr * 128 + (lane >> 4) * 4;
    const int cb = tn + wc * 64 + fr;
#pragma unroll
    for (int m = 0; m < 8; ++m) {
#pragma unroll
        for (int n = 0; n < 4; ++n) {
#pragma unroll
            for (int r = 0; r < 4; ++r) {
                float v = acc[m][n][r];
                const int row = rb + m * 16 + r;
                const int col = cb + n * 16;
                if (BIAS) v += bias[col];
                if (OUT_F16)
                    ((_Float16*)Cv)[coff + (long)row * ldc + col] = (_Float16)v;
                else
                    ((float*)Cv)[coff + (long)row * ldc + col] = v;
            }
        }
    }
}

extern "C" void kernel_launch(void* const* d_in, const int* in_sizes, int n_in,
                              void* d_out, int out_size, void* d_ws, size_t ws_size,
                              hipStream_t stream) {
    const float* x    = (const float*)d_in[0];   // (4,2048,2048)
    const float* wqkv = (const float*)d_in[1];   // (2048,6144)
    const float* wout = (const float*)d_in[2];   // (2048,2048)
    const float* bout = (const float*)d_in[3];   // (2048,)
    char* ws = (char*)d_ws;

    _Float16* qkv_h = (_Float16*)(ws);
    _Float16* x_h   = (_Float16*)(ws + 100663296);
    _Float16* wqkvT = (_Float16*)(ws + 134217728);
    _Float16* vT    = (_Float16*)(ws + 100663296);
    _Float16* woutT = (_Float16*)(ws);
    const bool batched = ws_size >= 234881024ULL;

    // 1. x -> f16
    f32_to_f16_vec<<<dim3(16384), dim3(256), 0, stream>>>(x, x_h);
    // 2. wqkv (2048x6144) -> wqkvT (6144x2048) f16
    transpose_f32_to_f16<<<dim3(192, 64), dim3(256), 0, stream>>>(wqkv, wqkvT, 2048, 6144);
    // 3. qkv = x @ wqkv  (M=8192,N=6144,K=2048) -> f16
    gemm256<true, false><<<dim3(24, 32, 1), dim3(512), 0, stream>>>(
        x_h, wqkvT, (void*)qkv_h, nullptr, 2048, 2048, 2048, 6144,
        1, 0L, 0L, 0L, 0L, 0L, 0L);
    // 4. RoPE in place on q,k halves (head-mixing rotation)
    rope_inplace<<<dim3(8192), dim3(256), 0, stream>>>(qkv_h);
    // 5. V transpose -> vT (b,h,d,s)
    v_transpose<<<dim3(64, 32, 8), dim3(256), 0, stream>>>(qkv_h, vT);

    if (batched) {
        _Float16* S16  = (_Float16*)(ws + 134217728);
        _Float16* aout = (_Float16*)(ws + 201326592);
        // 6. S = Q@K^T all 8 (b,h): M=N=2048,K=1024 -> f16
        gemm256<true, false><<<dim3(8, 8, 8), dim3(512), 0, stream>>>(
            qkv_h, qkv_h + 2048, (void*)S16, nullptr, 1024, 6144, 6144, 2048,
            2, 12582912L, 1024L, 12582912L, 1024L, 8388608L, 4194304L);
        // 7. softmax rows in place
        softmax_rows_f16<<<dim3(4096), dim3(256), 0, stream>>>(S16, 0.03125f);
        // 8. O = P@V: M=2048,N=1024,K=2048 -> aout (b,s,h*d)
        gemm256<true, false><<<dim3(4, 8, 8), dim3(512), 0, stream>>>(
            S16, vT, (void*)aout, nullptr, 2048, 2048, 2048, 2048,
            2, 8388608L, 4194304L, 4194304L, 2097152L, 4194304L, 1024L);
        // 9. wout -> woutT; out = aout @ wout + bout
        transpose_f32_to_f16<<<dim3(64, 64), dim3(256), 0, stream>>>(wout, woutT, 2048, 2048);
        gemm256<false, true><<<dim3(8, 32, 1), dim3(512), 0, stream>>>(
            aout, woutT, d_out, bout, 2048, 2048, 2048, 2048,
            1, 0L, 0L, 0L, 0L, 0L, 0L);
    } else {
        float*    S32  = (float*)(ws + 134217728);
        _Float16* aout = (_Float16*)(ws + 150994944);
        for (int z = 0; z < 8; ++z) {
            const _Float16* Az = qkv_h + (long)(z >> 1) * 12582912 + (z & 1) * 1024;
            gemm256<false, false><<<dim3(8, 8, 1), dim3(512), 0, stream>>>(
                Az, Az + 2048, (void*)S32, nullptr, 1024, 6144, 6144, 2048,
                1, 0L, 0L, 0L, 0L, 0L, 0L);
            softmax_rows_f32<<<dim3(512), dim3(256), 0, stream>>>(S32, 0.03125f);
            gemm256<true, false><<<dim3(4, 8, 1), dim3(512), 0, stream>>>(
                (const _Float16*)S32, vT + (long)z * 2097152,
                (void*)(aout + (long)(z >> 1) * 4194304 + (z & 1) * 1024), nullptr,
                2048, 4096, 2048, 2048, 1, 0L, 0L, 0L, 0L, 0L, 0L);
        }
        transpose_f32_to_f16<<<dim3(64, 64), dim3(256), 0, stream>>>(wout, woutT, 2048, 2048);
        gemm256<false, true><<<dim3(8, 32, 1), dim3(512), 0, stream>>>(
            aout, woutT, d_out, bout, 2048, 2048, 2048, 2048,
            1, 0L, 0L, 0L, 0L, 0L, 0L);
    }
}

// Round 4
// 536.054 us; speedup vs baseline: 1.3660x; 1.0240x over previous
//
#include <hip/hip_runtime.h>
#include <hip/hip_fp16.h>

typedef __attribute__((ext_vector_type(4))) float f32x4;
typedef __attribute__((ext_vector_type(8))) _Float16 f16x8;
typedef __attribute__((ext_vector_type(4))) _Float16 f16x4;

// ---------------- helpers ----------------
__device__ __forceinline__ void gload_lds16(const void* gp, void* lp) {
    __builtin_amdgcn_global_load_lds(
        (const __attribute__((address_space(1))) void*)gp,
        (__attribute__((address_space(3))) void*)lp, 16, 0, 0);
}

// ---------------- f32 -> f16 straight convert ----------------
__global__ void f32_to_f16_vec(const float* __restrict__ in, _Float16* __restrict__ out) {
    long i = ((long)blockIdx.x * 256 + threadIdx.x) * 4;
    f32x4 v = *(const f32x4*)(in + i);
    f16x4 h;
#pragma unroll
    for (int e = 0; e < 4; ++e) h[e] = (_Float16)v[e];
    *(f16x4*)(out + i) = h;
}

// ---------------- transpose + convert: in (R x C) f32 -> out (C x R) f16 ----------------
__global__ void transpose_f32_to_f16(const float* __restrict__ in, _Float16* __restrict__ out,
                                     int R, int C) {
    __shared__ _Float16 tile[32][36];
    const int c0 = blockIdx.x * 32, r0 = blockIdx.y * 32;
    const int t = threadIdx.x;
    const int r = t >> 3, c4 = (t & 7) * 4;
    f32x4 v = *(const f32x4*)(in + (long)(r0 + r) * C + c0 + c4);
    f16x4 h;
#pragma unroll
    for (int e = 0; e < 4; ++e) h[e] = (_Float16)v[e];
    *(f16x4*)&tile[r][c4] = h;
    __syncthreads();
    const int oc = t >> 3, o4 = (t & 7) * 4;
    f16x4 o;
#pragma unroll
    for (int e = 0; e < 4; ++e) o[e] = tile[o4 + e][oc];
    *(f16x4*)(out + (long)(c0 + oc) * R + r0 + o4) = o;
}

// ---------------- RoPE in-place on qkv rows (head-mixing: pair j with j+1024) ----------------
__global__ void rope_inplace(_Float16* __restrict__ qkv) {
    const int row = blockIdx.x;            // b*2048 + s
    const int s = row & 2047;
    const int j0 = threadIdx.x * 4;        // [0,1024)
    _Float16* base = qkv + (long)row * 6144;
    f16x4 q0 = *(const f16x4*)(base + j0);
    f16x4 q1 = *(const f16x4*)(base + 1024 + j0);
    f16x4 k0 = *(const f16x4*)(base + 2048 + j0);
    f16x4 k1 = *(const f16x4*)(base + 3072 + j0);
    f16x4 oq0, oq1, ok0, ok1;
#pragma unroll
    for (int e = 0; e < 4; ++e) {
        int fi = (j0 + e) & 511;
        float expo = (float)(2 * fi) * (1.0f / 1024.0f);
        float invf = 1.0f / powf(10000.0f, expo);
        float ang = (float)s * invf;
        float sn, cs;
        sincosf(ang, &sn, &cs);
        float a = (float)q0[e], b = (float)q1[e];
        oq0[e] = (_Float16)(a * cs - b * sn);
        oq1[e] = (_Float16)(b * cs + a * sn);
        float c = (float)k0[e], d = (float)k1[e];
        ok0[e] = (_Float16)(c * cs - d * sn);
        ok1[e] = (_Float16)(d * cs + c * sn);
    }
    *(f16x4*)(base + j0) = oq0;
    *(f16x4*)(base + 1024 + j0) = oq1;
    *(f16x4*)(base + 2048 + j0) = ok0;
    *(f16x4*)(base + 3072 + j0) = ok1;
}

// ---------------- V transpose: qkv v-part (b,s,h,d) -> vT (b,h,d,s) f16 ----------------
__global__ void v_transpose(const _Float16* __restrict__ qkv, _Float16* __restrict__ vT) {
    __shared__ _Float16 tile[32][36];
    const int z = blockIdx.z, b = z >> 1, h = z & 1;
    const int s0 = blockIdx.x * 32, d0 = blockIdx.y * 32;
    const int t = threadIdx.x;
    const int r = t >> 3, c4 = (t & 7) * 4;
    const _Float16* src = qkv + (long)(b * 2048 + s0 + r) * 6144 + 4096 + h * 1024 + d0 + c4;
    *(f16x4*)&tile[r][c4] = *(const f16x4*)src;
    __syncthreads();
    const int dr = t >> 3, sc = (t & 7) * 4;
    f16x4 o;
#pragma unroll
    for (int e = 0; e < 4; ++e) o[e] = tile[sc + e][dr];
    *(f16x4*)(vT + ((long)z * 1024 + d0 + dr) * 2048 + s0 + sc) = o;
}

// ---------------- softmax on f32 rows (2048), writes f16 P in place (row stride 4096 f16) ----------------
__global__ __launch_bounds__(256) void softmax_rows_f32(float* __restrict__ S, float scale) {
    const int wid = threadIdx.x >> 6, lane = threadIdx.x & 63;
    const long row = (long)blockIdx.x * 4 + wid;
    float* rp = S + row * 2048;
    f32x4 v[8];
    float mx = -1e30f;
#pragma unroll
    for (int i = 0; i < 8; ++i) {
        v[i] = *(const f32x4*)(rp + (i * 64 + lane) * 4);
#pragma unroll
        for (int e = 0; e < 4; ++e) mx = fmaxf(mx, v[i][e]);
    }
#pragma unroll
    for (int o = 32; o > 0; o >>= 1) mx = fmaxf(mx, __shfl_xor(mx, o, 64));
    float sum = 0.f;
#pragma unroll
    for (int i = 0; i < 8; ++i)
#pragma unroll
        for (int e = 0; e < 4; ++e) {
            float p = __expf(scale * (v[i][e] - mx));
            v[i][e] = p; sum += p;
        }
#pragma unroll
    for (int o = 32; o > 0; o >>= 1) sum += __shfl_xor(sum, o, 64);
    float inv = 1.0f / sum;
    _Float16* wp = (_Float16*)S + row * 4096;
#pragma unroll
    for (int i = 0; i < 8; ++i) {
        f16x4 h;
#pragma unroll
        for (int e = 0; e < 4; ++e) h[e] = (_Float16)(v[i][e] * inv);
        *(f16x4*)(wp + (i * 64 + lane) * 4) = h;
    }
}

// ---------------- softmax on f16 rows (2048), in place (row stride 2048 f16) ----------------
__global__ __launch_bounds__(256) void softmax_rows_f16(_Float16* __restrict__ S, float scale) {
    const int wid = threadIdx.x >> 6, lane = threadIdx.x & 63;
    const long row = (long)blockIdx.x * 4 + wid;
    _Float16* rp = S + row * 2048;
    f16x8 v[4];
    float f[32];
    float mx = -1e30f;
#pragma unroll
    for (int i = 0; i < 4; ++i) {
        v[i] = *(const f16x8*)(rp + i * 512 + lane * 8);
#pragma unroll
        for (int e = 0; e < 8; ++e) {
            f[i * 8 + e] = (float)v[i][e];
            mx = fmaxf(mx, f[i * 8 + e]);
        }
    }
#pragma unroll
    for (int o = 32; o > 0; o >>= 1) mx = fmaxf(mx, __shfl_xor(mx, o, 64));
    float sum = 0.f;
#pragma unroll
    for (int i = 0; i < 32; ++i) {
        float p = __expf(scale * (f[i] - mx));
        f[i] = p; sum += p;
    }
#pragma unroll
    for (int o = 32; o > 0; o >>= 1) sum += __shfl_xor(sum, o, 64);
    float inv = 1.0f / sum;
#pragma unroll
    for (int i = 0; i < 4; ++i) {
        f16x8 h;
#pragma unroll
        for (int e = 0; e < 8; ++e) h[e] = (_Float16)(f[i * 8 + e] * inv);
        *(f16x8*)(rp + i * 512 + lane * 8) = h;
    }
}

// ---------------- GEMM 256x256, BK=64, 8 waves, 2-buffer LDS, 4-phase/K-tile schedule ----------------
// C = A(MxK, lda) * B^T (B stored NxK row-major, ldb). K multiple of 64, NT=K/64 >= 2.
// LDS per buffer: A 256x64 f16 [0,32K), B 256x64 [32K,64K); rows 128 B; granule(16B) swizzle g^=(row&7).
// Stage writes are linear (global_load_lds); the inverse swizzle is applied to the GLOBAL source col.
// Schedule per K-tile g (quadrants Q00,Q01,Q11,Q10): stages g.1:A-h0(g+1) g.2:A-h1(g+1)
// g.3:B-h0(g+2) g.4:B-h1(g+2); gate once per tile: vmcnt(4).
template <bool OUT_F16, bool BIAS>
__global__ __launch_bounds__(512, 2)
void gemm256(const _Float16* __restrict__ A, const _Float16* __restrict__ B,
             void* __restrict__ Cv, const float* __restrict__ bias,
             int K, int lda, int ldb, int ldc, int zmod,
             long a1, long a2, long b1, long b2, long c1, long c2) {
    __shared__ char lds[131072];
    const int z = blockIdx.z, zq = z / zmod, zr = z - zq * zmod;
    A += zq * a1 + zr * a2;
    B += zq * b1 + zr * b2;
    const long coff = zq * c1 + zr * c2;
    const int tm = blockIdx.y * 256, tn = blockIdx.x * 256;
    const int t = threadIdx.x;
    const int lane = t & 63, wid = t >> 6;
    const int wr = wid >> 2, wc = wid & 3;     // wave tile: rows wr*128, cols wc*64
    const int fr = lane & 15, kg = lane >> 4;

    // staging source (inverse-swizzled global col): thread covers row wid*16+(lane>>3) (+8 for 2nd load)
    const int strow = wid * 16 + (lane >> 3);
    const int stcol = ((lane & 7) ^ (lane >> 3)) * 8;
    const _Float16* gA = A + (long)(tm + strow) * lda + stcol;
    const _Float16* gB = B + (long)(tn + strow) * ldb + stcol;
    char* const ldsw = lds + wid * 2048;       // wave's linear chunk base (+1024 for 2nd load)

    // ds_read swizzled granule offsets (per lane, k-half h in {0,1})
    const int sw0 = 16 * ((0 * 4 + kg) ^ (fr & 7));
    const int sw1 = 16 * ((1 * 4 + kg) ^ (fr & 7));

    const int NT = K >> 6;
    f32x4 acc[8][4] = {};

    auto stageA = [&](int tt, int h) {
        const _Float16* s = gA + (long)(h * 128) * lda + tt * 64;
        char* d = ldsw + (tt & 1) * 65536 + h * 16384;
        gload_lds16(s, d);
        gload_lds16(s + (long)8 * lda, d + 1024);
    };
    auto stageB = [&](int tt, int h) {
        const _Float16* s = gB + (long)(h * 128) * ldb + tt * 64;
        char* d = ldsw + (tt & 1) * 65536 + 32768 + h * 16384;
        gload_lds16(s, d);
        gload_lds16(s + (long)8 * ldb, d + 1024);
    };

    // prologue: tile0 (B then A), tile1 B halves; gate tile0
    stageB(0, 0); stageB(0, 1); stageA(0, 0); stageA(0, 1);
    stageB(1, 0); stageB(1, 1);
    asm volatile("s_waitcnt vmcnt(4)" ::: "memory");
    __builtin_amdgcn_s_barrier();

    f16x8 af[4][2], bf0[2][2], bf1[2][2];
    const int arow = (wr * 128 + fr) * 128;          // byte row base for A frags
    const int brow = 32768 + (wc * 64 + fr) * 128;   // byte row base for B frags

    for (int g = 0; g < NT; ++g) {
        const char* buf = lds + (g & 1) * 65536;
        // ---- phase 1: Q(0,0) — read A(mg=0) + B(ng=0); stage A-h0(g+1)
#pragma unroll
        for (int m = 0; m < 4; ++m) {
            af[m][0] = *(const f16x8*)(buf + arow + m * 2048 + sw0);
            af[m][1] = *(const f16x8*)(buf + arow + m * 2048 + sw1);
        }
#pragma unroll
        for (int n = 0; n < 2; ++n) {
            bf0[n][0] = *(const f16x8*)(buf + brow + n * 2048 + sw0);
            bf0[n][1] = *(const f16x8*)(buf + brow + n * 2048 + sw1);
        }
        if (g + 1 < NT) stageA(g + 1, 0);
        __builtin_amdgcn_s_barrier();
        asm volatile("s_waitcnt lgkmcnt(0)" ::: "memory");
        __builtin_amdgcn_sched_barrier(0);
        __builtin_amdgcn_s_setprio(1);
#pragma unroll
        for (int m = 0; m < 4; ++m)
#pragma unroll
            for (int n = 0; n < 2; ++n)
#pragma unroll
                for (int k = 0; k < 2; ++k)
                    acc[m][n] = __builtin_amdgcn_mfma_f32_16x16x32_f16(af[m][k], bf0[n][k], acc[m][n], 0, 0, 0);
        __builtin_amdgcn_s_setprio(0);
        __builtin_amdgcn_s_barrier();
        // ---- phase 2: Q(0,1) — read B(ng=1); stage A-h1(g+1)
#pragma unroll
        for (int n = 0; n < 2; ++n) {
            bf1[n][0] = *(const f16x8*)(buf + brow + 4096 + n * 2048 + sw0);
            bf1[n][1] = *(const f16x8*)(buf + brow + 4096 + n * 2048 + sw1);
        }
        if (g + 1 < NT) stageA(g + 1, 1);
        __builtin_amdgcn_s_barrier();
        asm volatile("s_waitcnt lgkmcnt(0)" ::: "memory");
        __builtin_amdgcn_sched_barrier(0);
        __builtin_amdgcn_s_setprio(1);
#pragma unroll
        for (int m = 0; m < 4; ++m)
#pragma unroll
            for (int n = 0; n < 2; ++n)
#pragma unroll
                for (int k = 0; k < 2; ++k)
                    acc[m][n + 2] = __builtin_amdgcn_mfma_f32_16x16x32_f16(af[m][k], bf1[n][k], acc[m][n + 2], 0, 0, 0);
        __builtin_amdgcn_s_setprio(0);
        __builtin_amdgcn_s_barrier();
        // ---- phase 3: Q(1,1) — read A(mg=1); stage B-h0(g+2)
#pragma unroll
        for (int m = 0; m < 4; ++m) {
            af[m][0] = *(const f16x8*)(buf + arow + 8192 + m * 2048 + sw0);
            af[m][1] = *(const f16x8*)(buf + arow + 8192 + m * 2048 + sw1);
        }
        if (g + 2 < NT) stageB(g + 2, 0);
        __builtin_amdgcn_s_barrier();
        asm volatile("s_waitcnt lgkmcnt(0)" ::: "memory");
        __builtin_amdgcn_sched_barrier(0);
        __builtin_amdgcn_s_setprio(1);
#pragma unroll
        for (int m = 0; m < 4; ++m)
#pragma unroll
            for (int n = 0; n < 2; ++n)
#pragma unroll
                for (int k = 0; k < 2; ++k)
                    acc[m + 4][n + 2] = __builtin_amdgcn_mfma_f32_16x16x32_f16(af[m][k], bf1[n][k], acc[m + 4][n + 2], 0, 0, 0);
        __builtin_amdgcn_s_setprio(0);
        __builtin_amdgcn_s_barrier();
        // ---- phase 4: Q(1,0) — no reads (reuse bf0); stage B-h1(g+2)
        if (g + 2 < NT) stageB(g + 2, 1);
        __builtin_amdgcn_s_barrier();
        __builtin_amdgcn_s_setprio(1);
#pragma unroll
        for (int m = 0; m < 4; ++m)
#pragma unroll
            for (int n = 0; n < 2; ++n)
#pragma unroll
                for (int k = 0; k < 2; ++k)
                    acc[m + 4][n] = __builtin_amdgcn_mfma_f32_16x16x32_f16(af[m][k], bf0[n][k], acc[m + 4][n], 0, 0, 0);
        __builtin_amdgcn_s_setprio(0);
        // ---- gate for tile g+1 (once per K-tile; counted, never drains mid-loop)
        if (g + 2 < NT)      asm volatile("s_waitcnt vmcnt(4)" ::: "memory");
        else if (g + 1 < NT) asm volatile("s_waitcnt vmcnt(0)" ::: "memory");
        __builtin_amdgcn_s_barrier();
    }

    // epilogue: C/D layout col = lane&15, row = (lane>>4)*4 + r
    const int rb = tm + wr * 128 + (lane >> 4) * 4;
    const int cb = tn + wc * 64 + fr;
#pragma unroll
    for (int m = 0; m < 8; ++m) {
#pragma unroll
        for (int n = 0; n < 4; ++n) {
#pragma unroll
            for (int r = 0; r < 4; ++r) {
                float v = acc[m][n][r];
                const int row = rb + m * 16 + r;
                const int col = cb + n * 16;
                if (BIAS) v += bias[col];
                if (OUT_F16)
                    ((_Float16*)Cv)[coff + (long)row * ldc + col] = (_Float16)v;
                else
                    ((float*)Cv)[coff + (long)row * ldc + col] = v;
            }
        }
    }
}

extern "C" void kernel_launch(void* const* d_in, const int* in_sizes, int n_in,
                              void* d_out, int out_size, void* d_ws, size_t ws_size,
                              hipStream_t stream) {
    const float* x    = (const float*)d_in[0];   // (4,2048,2048)
    const float* wqkv = (const float*)d_in[1];   // (2048,6144)
    const float* wout = (const float*)d_in[2];   // (2048,2048)
    const float* bout = (const float*)d_in[3];   // (2048,)
    char* ws = (char*)d_ws;

    _Float16* qkv_h = (_Float16*)(ws);
    _Float16* x_h   = (_Float16*)(ws + 100663296);
    _Float16* wqkvT = (_Float16*)(ws + 134217728);
    _Float16* vT    = (_Float16*)(ws + 100663296);
    _Float16* woutT = (_Float16*)(ws);
    const bool batched = ws_size >= 234881024ULL;

    // 1. x -> f16
    f32_to_f16_vec<<<dim3(16384), dim3(256), 0, stream>>>(x, x_h);
    // 2. wqkv (2048x6144) -> wqkvT (6144x2048) f16
    transpose_f32_to_f16<<<dim3(192, 64), dim3(256), 0, stream>>>(wqkv, wqkvT, 2048, 6144);
    // 3. qkv = x @ wqkv  (M=8192,N=6144,K=2048) -> f16
    gemm256<true, false><<<dim3(24, 32, 1), dim3(512), 0, stream>>>(
        x_h, wqkvT, (void*)qkv_h, nullptr, 2048, 2048, 2048, 6144,
        1, 0L, 0L, 0L, 0L, 0L, 0L);
    // 4. RoPE in place on q,k halves (head-mixing rotation)
    rope_inplace<<<dim3(8192), dim3(256), 0, stream>>>(qkv_h);
    // 5. V transpose -> vT (b,h,d,s)
    v_transpose<<<dim3(64, 32, 8), dim3(256), 0, stream>>>(qkv_h, vT);

    if (batched) {
        _Float16* S16  = (_Float16*)(ws + 134217728);
        _Float16* aout = (_Float16*)(ws + 201326592);
        // 6. S = Q@K^T all 8 (b,h): M=N=2048,K=1024 -> f16
        gemm256<true, false><<<dim3(8, 8, 8), dim3(512), 0, stream>>>(
            qkv_h, qkv_h + 2048, (void*)S16, nullptr, 1024, 6144, 6144, 2048,
            2, 12582912L, 1024L, 12582912L, 1024L, 8388608L, 4194304L);
        // 7. softmax rows in place
        softmax_rows_f16<<<dim3(4096), dim3(256), 0, stream>>>(S16, 0.03125f);
        // 8. O = P@V: M=2048,N=1024,K=2048 -> aout (b,s,h*d)
        gemm256<true, false><<<dim3(4, 8, 8), dim3(512), 0, stream>>>(
            S16, vT, (void*)aout, nullptr, 2048, 2048, 2048, 2048,
            2, 8388608L, 4194304L, 4194304L, 2097152L, 4194304L, 1024L);
        // 9. wout -> woutT; out = aout @ wout + bout
        transpose_f32_to_f16<<<dim3(64, 64), dim3(256), 0, stream>>>(wout, woutT, 2048, 2048);
        gemm256<false, true><<<dim3(8, 32, 1), dim3(512), 0, stream>>>(
            aout, woutT, d_out, bout, 2048, 2048, 2048, 2048,
            1, 0L, 0L, 0L, 0L, 0L, 0L);
    } else {
        float*    S32  = (float*)(ws + 134217728);
        _Float16* aout = (_Float16*)(ws + 150994944);
        for (int z = 0; z < 8; ++z) {
            const _Float16* Az = qkv_h + (long)(z >> 1) * 12582912 + (z & 1) * 1024;
            gemm256<false, false><<<dim3(8, 8, 1), dim3(512), 0, stream>>>(
                Az, Az + 2048, (void*)S32, nullptr, 1024, 6144, 6144, 2048,
                1, 0L, 0L, 0L, 0L, 0L, 0L);
            softmax_rows_f32<<<dim3(512), dim3(256), 0, stream>>>(S32, 0.03125f);
            gemm256<true, false><<<dim3(4, 8, 1), dim3(512), 0, stream>>>(
                (const _Float16*)S32, vT + (long)z * 2097152,
                (void*)(aout + (long)(z >> 1) * 4194304 + (z & 1) * 1024), nullptr,
                2048, 4096, 2048, 2048, 1, 0L, 0L, 0L, 0L, 0L, 0L);
        }
        transpose_f32_to_f16<<<dim3(64, 64), dim3(256), 0, stream>>>(wout, woutT, 2048, 2048);
        gemm256<false, true><<<dim3(8, 32, 1), dim3(512), 0, stream>>>(
            aout, woutT, d_out, bout, 2048, 2048, 2048, 2048,
            1, 0L, 0L, 0L, 0L, 0L, 0L);
    }
}

// Round 5
// 520.130 us; speedup vs baseline: 1.4078x; 1.0306x over previous
//
#include <hip/hip_runtime.h>
#include <hip/hip_fp16.h>

typedef __attribute__((ext_vector_type(4))) float f32x4;
typedef __attribute__((ext_vector_type(8))) _Float16 f16x8;
typedef __attribute__((ext_vector_type(4))) _Float16 f16x4;

// ---------------- helpers ----------------
__device__ __forceinline__ void gload_lds16(const void* gp, void* lp) {
    __builtin_amdgcn_global_load_lds(
        (const __attribute__((address_space(1))) void*)gp,
        (__attribute__((address_space(3))) void*)lp, 16, 0, 0);
}

// ---------------- RoPE tables: cos/sin (2048 x 512) f32 ----------------
__global__ void rope_tables_k(float* __restrict__ cosT, float* __restrict__ sinT) {
    int idx = blockIdx.x * 256 + threadIdx.x;   // 2048*512 total
    int s = idx >> 9, j = idx & 511;
    float invf = exp2f(-13.287712379549449f * (float)j * (1.0f / 512.0f)); // 10000^(-j/512)
    float ang = (float)s * invf;
    float sn, cs;
    sincosf(ang, &sn, &cs);
    cosT[idx] = cs;
    sinT[idx] = sn;
}

// ---------------- f32 -> f16 straight convert ----------------
__global__ void f32_to_f16_vec(const float* __restrict__ in, _Float16* __restrict__ out) {
    long i = ((long)blockIdx.x * 256 + threadIdx.x) * 4;
    f32x4 v = *(const f32x4*)(in + i);
    f16x4 h;
#pragma unroll
    for (int e = 0; e < 4; ++e) h[e] = (_Float16)v[e];
    *(f16x4*)(out + i) = h;
}

// ---------------- transpose + convert: in (R x C) f32 -> out (C x R) f16 ----------------
__global__ void transpose_f32_to_f16(const float* __restrict__ in, _Float16* __restrict__ out,
                                     int R, int C) {
    __shared__ _Float16 tile[32][36];
    const int c0 = blockIdx.x * 32, r0 = blockIdx.y * 32;
    const int t = threadIdx.x;
    const int r = t >> 3, c4 = (t & 7) * 4;
    f32x4 v = *(const f32x4*)(in + (long)(r0 + r) * C + c0 + c4);
    f16x4 h;
#pragma unroll
    for (int e = 0; e < 4; ++e) h[e] = (_Float16)v[e];
    *(f16x4*)&tile[r][c4] = h;
    __syncthreads();
    const int oc = t >> 3, o4 = (t & 7) * 4;
    f16x4 o;
#pragma unroll
    for (int e = 0; e < 4; ++e) o[e] = tile[o4 + e][oc];
    *(f16x4*)(out + (long)(c0 + oc) * R + r0 + o4) = o;
}

// ---------------- RoPE in-place on qkv rows (head-mixing: pair j with j+1024) ----------------
__global__ void rope_inplace(_Float16* __restrict__ qkv, const float* __restrict__ cosT,
                             const float* __restrict__ sinT) {
    const int row = blockIdx.x;            // b*2048 + s
    const int s = row & 2047;
    const int j0 = threadIdx.x * 4;        // [0,1024)
    _Float16* base = qkv + (long)row * 6144;
    f16x4 q0 = *(const f16x4*)(base + j0);
    f16x4 q1 = *(const f16x4*)(base + 1024 + j0);
    f16x4 k0 = *(const f16x4*)(base + 2048 + j0);
    f16x4 k1 = *(const f16x4*)(base + 3072 + j0);
    const int jj = j0 & 511;
    f32x4 cs = *(const f32x4*)(cosT + (long)s * 512 + jj);
    f32x4 sn = *(const f32x4*)(sinT + (long)s * 512 + jj);
    f16x4 oq0, oq1, ok0, ok1;
#pragma unroll
    for (int e = 0; e < 4; ++e) {
        float a = (float)q0[e], b = (float)q1[e];
        oq0[e] = (_Float16)(a * cs[e] - b * sn[e]);
        oq1[e] = (_Float16)(b * cs[e] + a * sn[e]);
        float c = (float)k0[e], d = (float)k1[e];
        ok0[e] = (_Float16)(c * cs[e] - d * sn[e]);
        ok1[e] = (_Float16)(d * cs[e] + c * sn[e]);
    }
    *(f16x4*)(base + j0) = oq0;
    *(f16x4*)(base + 1024 + j0) = oq1;
    *(f16x4*)(base + 2048 + j0) = ok0;
    *(f16x4*)(base + 3072 + j0) = ok1;
}

// ---------------- V transpose: qkv v-part (b,s,h,d) -> vT (b,h,d,s) f16 ----------------
__global__ void v_transpose(const _Float16* __restrict__ qkv, _Float16* __restrict__ vT) {
    __shared__ _Float16 tile[32][36];
    const int z = blockIdx.z, b = z >> 1, h = z & 1;
    const int s0 = blockIdx.x * 32, d0 = blockIdx.y * 32;
    const int t = threadIdx.x;
    const int r = t >> 3, c4 = (t & 7) * 4;
    const _Float16* src = qkv + (long)(b * 2048 + s0 + r) * 6144 + 4096 + h * 1024 + d0 + c4;
    *(f16x4*)&tile[r][c4] = *(const f16x4*)src;
    __syncthreads();
    const int dr = t >> 3, sc = (t & 7) * 4;
    f16x4 o;
#pragma unroll
    for (int e = 0; e < 4; ++e) o[e] = tile[sc + e][dr];
    *(f16x4*)(vT + ((long)z * 1024 + d0 + dr) * 2048 + s0 + sc) = o;
}

// ---------------- softmax on f32 rows (2048), writes f16 P in place (row stride 4096 f16) ----------------
__global__ __launch_bounds__(256) void softmax_rows_f32(float* __restrict__ S, float scale) {
    const int wid = threadIdx.x >> 6, lane = threadIdx.x & 63;
    const long row = (long)blockIdx.x * 4 + wid;
    float* rp = S + row * 2048;
    f32x4 v[8];
    float mx = -1e30f;
#pragma unroll
    for (int i = 0; i < 8; ++i) {
        v[i] = *(const f32x4*)(rp + (i * 64 + lane) * 4);
#pragma unroll
        for (int e = 0; e < 4; ++e) mx = fmaxf(mx, v[i][e]);
    }
#pragma unroll
    for (int o = 32; o > 0; o >>= 1) mx = fmaxf(mx, __shfl_xor(mx, o, 64));
    float sum = 0.f;
#pragma unroll
    for (int i = 0; i < 8; ++i)
#pragma unroll
        for (int e = 0; e < 4; ++e) {
            float p = __expf(scale * (v[i][e] - mx));
            v[i][e] = p; sum += p;
        }
#pragma unroll
    for (int o = 32; o > 0; o >>= 1) sum += __shfl_xor(sum, o, 64);
    float inv = 1.0f / sum;
    _Float16* wp = (_Float16*)S + row * 4096;
#pragma unroll
    for (int i = 0; i < 8; ++i) {
        f16x4 h;
#pragma unroll
        for (int e = 0; e < 4; ++e) h[e] = (_Float16)(v[i][e] * inv);
        *(f16x4*)(wp + (i * 64 + lane) * 4) = h;
    }
}

// ---------------- softmax on f16 rows (2048), in place (row stride 2048 f16) ----------------
__global__ __launch_bounds__(256) void softmax_rows_f16(_Float16* __restrict__ S, float scale) {
    const int wid = threadIdx.x >> 6, lane = threadIdx.x & 63;
    const long row = (long)blockIdx.x * 4 + wid;
    _Float16* rp = S + row * 2048;
    f16x8 v[4];
    float f[32];
    float mx = -1e30f;
#pragma unroll
    for (int i = 0; i < 4; ++i) {
        v[i] = *(const f16x8*)(rp + i * 512 + lane * 8);
#pragma unroll
        for (int e = 0; e < 8; ++e) {
            f[i * 8 + e] = (float)v[i][e];
            mx = fmaxf(mx, f[i * 8 + e]);
        }
    }
#pragma unroll
    for (int o = 32; o > 0; o >>= 1) mx = fmaxf(mx, __shfl_xor(mx, o, 64));
    float sum = 0.f;
#pragma unroll
    for (int i = 0; i < 32; ++i) {
        float p = __expf(scale * (f[i] - mx));
        f[i] = p; sum += p;
    }
#pragma unroll
    for (int o = 32; o > 0; o >>= 1) sum += __shfl_xor(sum, o, 64);
    float inv = 1.0f / sum;
#pragma unroll
    for (int i = 0; i < 4; ++i) {
        f16x8 h;
#pragma unroll
        for (int e = 0; e < 8; ++e) h[e] = (_Float16)(f[i * 8 + e] * inv);
        *(f16x8*)(rp + i * 512 + lane * 8) = h;
    }
}

// ---------------- GEMM 256x256, BK=64, 8 waves, 2-buffer LDS, 4-phase/K-tile schedule ----------------
// C = A(MxK, lda) * B^T (B stored NxK row-major, ldb). K multiple of 64, NT=K/64 >= 2.
// LDS per buffer: A 256x64 f16 [0,32K), B [32K,64K); rows 128 B; granule(16B) swizzle g^=(row&7).
// Stage writes linear (global_load_lds); inverse swizzle applied to the GLOBAL source col.
// NO hand fences inside phases: the compiler's own fine-grained lgkmcnt interleaves
// ds_read completion with the MFMA cluster (this was the round-4 serialization bug).
template <bool OUT_F16, bool BIAS>
__global__ __launch_bounds__(512, 2)
void gemm256(const _Float16* __restrict__ A, const _Float16* __restrict__ B,
             void* __restrict__ Cv, const float* __restrict__ bias,
             int K, int lda, int ldb, int ldc, int zmod,
             long a1, long a2, long b1, long b2, long c1, long c2) {
    __shared__ char lds[131072];
    const int z = blockIdx.z, zq = z / zmod, zr = z - zq * zmod;
    A += zq * a1 + zr * a2;
    B += zq * b1 + zr * b2;
    const long coff = zq * c1 + zr * c2;
    const int tm = blockIdx.y * 256, tn = blockIdx.x * 256;
    const int t = threadIdx.x;
    const int lane = t & 63, wid = t >> 6;
    const int wr = wid >> 2, wc = wid & 3;     // wave tile: rows wr*128, cols wc*64
    const int fr = lane & 15, kg = lane >> 4;

    // staging source (inverse-swizzled global col)
    const int strow = wid * 16 + (lane >> 3);
    const int stcol = ((lane & 7) ^ (lane >> 3)) * 8;
    const _Float16* gA = A + (long)(tm + strow) * lda + stcol;
    const _Float16* gB = B + (long)(tn + strow) * ldb + stcol;
    char* const ldsw = lds + wid * 2048;       // wave's linear chunk base (+1024 for 2nd load)

    // ds_read swizzled granule offsets (per lane, k-half h in {0,1})
    const int sw0 = 16 * ((0 * 4 + kg) ^ (fr & 7));
    const int sw1 = 16 * ((1 * 4 + kg) ^ (fr & 7));

    const int NT = K >> 6;
    f32x4 acc[8][4] = {};

    auto stageA = [&](int tt, int h) {
        const _Float16* s = gA + (long)(h * 128) * lda + tt * 64;
        char* d = ldsw + (tt & 1) * 65536 + h * 16384;
        gload_lds16(s, d);
        gload_lds16(s + (long)8 * lda, d + 1024);
    };
    auto stageB = [&](int tt, int h) {
        const _Float16* s = gB + (long)(h * 128) * ldb + tt * 64;
        char* d = ldsw + (tt & 1) * 65536 + 32768 + h * 16384;
        gload_lds16(s, d);
        gload_lds16(s + (long)8 * ldb, d + 1024);
    };

    // prologue: tile0 (B then A), tile1 B halves; gate tile0
    stageB(0, 0); stageB(0, 1); stageA(0, 0); stageA(0, 1);
    stageB(1, 0); stageB(1, 1);
    asm volatile("s_waitcnt vmcnt(4)" ::: "memory");
    __builtin_amdgcn_s_barrier();

    f16x8 af[4][2], bf0[2][2], bf1[2][2];
    const int arow = (wr * 128 + fr) * 128;          // byte row base for A frags
    const int brow = 32768 + (wc * 64 + fr) * 128;   // byte row base for B frags

    for (int g = 0; g < NT; ++g) {
        const char* buf = lds + (g & 1) * 65536;
        // ---- phase 1: Q(0,0) — read A(mg=0) + B(ng=0); stage A-h0(g+1)
#pragma unroll
        for (int m = 0; m < 4; ++m) {
            af[m][0] = *(const f16x8*)(buf + arow + m * 2048 + sw0);
            af[m][1] = *(const f16x8*)(buf + arow + m * 2048 + sw1);
        }
#pragma unroll
        for (int n = 0; n < 2; ++n) {
            bf0[n][0] = *(const f16x8*)(buf + brow + n * 2048 + sw0);
            bf0[n][1] = *(const f16x8*)(buf + brow + n * 2048 + sw1);
        }
        if (g + 1 < NT) stageA(g + 1, 0);
        __builtin_amdgcn_s_barrier();
        __builtin_amdgcn_s_setprio(1);
#pragma unroll
        for (int m = 0; m < 4; ++m)
#pragma unroll
            for (int n = 0; n < 2; ++n)
#pragma unroll
                for (int k = 0; k < 2; ++k)
                    acc[m][n] = __builtin_amdgcn_mfma_f32_16x16x32_f16(af[m][k], bf0[n][k], acc[m][n], 0, 0, 0);
        __builtin_amdgcn_s_setprio(0);
        __builtin_amdgcn_s_barrier();
        // ---- phase 2: Q(0,1) — read B(ng=1); stage A-h1(g+1)
#pragma unroll
        for (int n = 0; n < 2; ++n) {
            bf1[n][0] = *(const f16x8*)(buf + brow + 4096 + n * 2048 + sw0);
            bf1[n][1] = *(const f16x8*)(buf + brow + 4096 + n * 2048 + sw1);
        }
        if (g + 1 < NT) stageA(g + 1, 1);
        __builtin_amdgcn_s_barrier();
        __builtin_amdgcn_s_setprio(1);
#pragma unroll
        for (int m = 0; m < 4; ++m)
#pragma unroll
            for (int n = 0; n < 2; ++n)
#pragma unroll
                for (int k = 0; k < 2; ++k)
                    acc[m][n + 2] = __builtin_amdgcn_mfma_f32_16x16x32_f16(af[m][k], bf1[n][k], acc[m][n + 2], 0, 0, 0);
        __builtin_amdgcn_s_setprio(0);
        __builtin_amdgcn_s_barrier();
        // ---- phase 3: Q(1,1) — read A(mg=1); stage B-h0(g+2)
#pragma unroll
        for (int m = 0; m < 4; ++m) {
            af[m][0] = *(const f16x8*)(buf + arow + 8192 + m * 2048 + sw0);
            af[m][1] = *(const f16x8*)(buf + arow + 8192 + m * 2048 + sw1);
        }
        if (g + 2 < NT) stageB(g + 2, 0);
        __builtin_amdgcn_s_barrier();
        __builtin_amdgcn_s_setprio(1);
#pragma unroll
        for (int m = 0; m < 4; ++m)
#pragma unroll
            for (int n = 0; n < 2; ++n)
#pragma unroll
                for (int k = 0; k < 2; ++k)
                    acc[m + 4][n + 2] = __builtin_amdgcn_mfma_f32_16x16x32_f16(af[m][k], bf1[n][k], acc[m + 4][n + 2], 0, 0, 0);
        __builtin_amdgcn_s_setprio(0);
        __builtin_amdgcn_s_barrier();
        // ---- phase 4: Q(1,0) — no reads (reuse bf0); stage B-h1(g+2)
        if (g + 2 < NT) stageB(g + 2, 1);
        __builtin_amdgcn_s_barrier();
        __builtin_amdgcn_s_setprio(1);
#pragma unroll
        for (int m = 0; m < 4; ++m)
#pragma unroll
            for (int n = 0; n < 2; ++n)
#pragma unroll
                for (int k = 0; k < 2; ++k)
                    acc[m + 4][n] = __builtin_amdgcn_mfma_f32_16x16x32_f16(af[m][k], bf0[n][k], acc[m + 4][n], 0, 0, 0);
        __builtin_amdgcn_s_setprio(0);
        // ---- gate for tile g+1 (once per K-tile; counted, never drains mid-loop)
        if (g + 2 < NT)      asm volatile("s_waitcnt vmcnt(4)" ::: "memory");
        else if (g + 1 < NT) asm volatile("s_waitcnt vmcnt(0)" ::: "memory");
        __builtin_amdgcn_s_barrier();
    }

    // epilogue: C/D layout col = lane&15, row = (lane>>4)*4 + r
    const int rb = tm + wr * 128 + (lane >> 4) * 4;
    const int cb = tn + wc * 64 + fr;
#pragma unroll
    for (int m = 0; m < 8; ++m) {
#pragma unroll
        for (int n = 0; n < 4; ++n) {
#pragma unroll
            for (int r = 0; r < 4; ++r) {
                float v = acc[m][n][r];
                const int row = rb + m * 16 + r;
                const int col = cb + n * 16;
                if (BIAS) v += bias[col];
                if (OUT_F16)
                    ((_Float16*)Cv)[coff + (long)row * ldc + col] = (_Float16)v;
                else
                    ((float*)Cv)[coff + (long)row * ldc + col] = v;
            }
        }
    }
}

extern "C" void kernel_launch(void* const* d_in, const int* in_sizes, int n_in,
                              void* d_out, int out_size, void* d_ws, size_t ws_size,
                              hipStream_t stream) {
    const float* x    = (const float*)d_in[0];   // (4,2048,2048)
    const float* wqkv = (const float*)d_in[1];   // (2048,6144)
    const float* wout = (const float*)d_in[2];   // (2048,2048)
    const float* bout = (const float*)d_in[3];   // (2048,)
    char* ws = (char*)d_ws;

    _Float16* qkv_h = (_Float16*)(ws);
    _Float16* x_h   = (_Float16*)(ws + 100663296);
    _Float16* wqkvT = (_Float16*)(ws + 134217728);
    _Float16* vT    = (_Float16*)(ws + 100663296);
    float*    cosT  = (float*)(ws + 100663296);   // alias: lives between QKV GEMM and v_transpose
    float*    sinT  = (float*)(ws + 104857600);
    _Float16* woutT = (_Float16*)(ws);
    const bool batched = ws_size >= 234881024ULL;

    // 1. x -> f16
    f32_to_f16_vec<<<dim3(16384), dim3(256), 0, stream>>>(x, x_h);
    // 2. wqkv (2048x6144) -> wqkvT (6144x2048) f16
    transpose_f32_to_f16<<<dim3(192, 64), dim3(256), 0, stream>>>(wqkv, wqkvT, 2048, 6144);
    // 3. qkv = x @ wqkv  (M=8192,N=6144,K=2048) -> f16
    gemm256<true, false><<<dim3(24, 32, 1), dim3(512), 0, stream>>>(
        x_h, wqkvT, (void*)qkv_h, nullptr, 2048, 2048, 2048, 6144,
        1, 0L, 0L, 0L, 0L, 0L, 0L);
    // 4. RoPE tables (x_h now dead; tables alias that region)
    rope_tables_k<<<dim3(4096), dim3(256), 0, stream>>>(cosT, sinT);
    // 5. RoPE in place on q,k halves (head-mixing rotation)
    rope_inplace<<<dim3(8192), dim3(256), 0, stream>>>(qkv_h, cosT, sinT);
    // 6. V transpose -> vT (b,h,d,s)  (overwrites table region; tables dead)
    v_transpose<<<dim3(64, 32, 8), dim3(256), 0, stream>>>(qkv_h, vT);

    if (batched) {
        _Float16* S16  = (_Float16*)(ws + 134217728);
        _Float16* aout = (_Float16*)(ws + 201326592);
        // 7. S = Q@K^T all 8 (b,h): M=N=2048,K=1024 -> f16
        gemm256<true, false><<<dim3(8, 8, 8), dim3(512), 0, stream>>>(
            qkv_h, qkv_h + 2048, (void*)S16, nullptr, 1024, 6144, 6144, 2048,
            2, 12582912L, 1024L, 12582912L, 1024L, 8388608L, 4194304L);
        // 8. softmax rows in place
        softmax_rows_f16<<<dim3(4096), dim3(256), 0, stream>>>(S16, 0.03125f);
        // 9. O = P@V: M=2048,N=1024,K=2048 -> aout (b,s,h*d)
        gemm256<true, false><<<dim3(4, 8, 8), dim3(512), 0, stream>>>(
            S16, vT, (void*)aout, nullptr, 2048, 2048, 2048, 2048,
            2, 8388608L, 4194304L, 4194304L, 2097152L, 4194304L, 1024L);
        // 10. wout -> woutT; out = aout @ wout + bout
        transpose_f32_to_f16<<<dim3(64, 64), dim3(256), 0, stream>>>(wout, woutT, 2048, 2048);
        gemm256<false, true><<<dim3(8, 32, 1), dim3(512), 0, stream>>>(
            aout, woutT, d_out, bout, 2048, 2048, 2048, 2048,
            1, 0L, 0L, 0L, 0L, 0L, 0L);
    } else {
        float*    S32  = (float*)(ws + 134217728);
        _Float16* aout = (_Float16*)(ws + 150994944);
        for (int z = 0; z < 8; ++z) {
            const _Float16* Az = qkv_h + (long)(z >> 1) * 12582912 + (z & 1) * 1024;
            gemm256<false, false><<<dim3(8, 8, 1), dim3(512), 0, stream>>>(
                Az, Az + 2048, (void*)S32, nullptr, 1024, 6144, 6144, 2048,
                1, 0L, 0L, 0L, 0L, 0L, 0L);
            softmax_rows_f32<<<dim3(512), dim3(256), 0, stream>>>(S32, 0.03125f);
            gemm256<true, false><<<dim3(4, 8, 1), dim3(512), 0, stream>>>(
                (const _Float16*)S32, vT + (long)z * 2097152,
                (void*)(aout + (long)(z >> 1) * 4194304 + (z & 1) * 1024), nullptr,
                2048, 4096, 2048, 2048, 1, 0L, 0L, 0L, 0L, 0L, 0L);
        }
        transpose_f32_to_f16<<<dim3(64, 64), dim3(256), 0, stream>>>(wout, woutT, 2048, 2048);
        gemm256<false, true><<<dim3(8, 32, 1), dim3(512), 0, stream>>>(
            aout, woutT, d_out, bout, 2048, 2048, 2048, 2048,
            1, 0L, 0L, 0L, 0L, 0L, 0L);
    }
}